// Round 3
// baseline (539.223 us; speedup 1.0000x reference)
//
#include <hip/hip_runtime.h>

typedef unsigned short u16;
typedef unsigned int   u32;
typedef __bf16 bf16;
typedef float f32x4  __attribute__((ext_vector_type(4)));
typedef bf16  bf16x8 __attribute__((ext_vector_type(8)));

__device__ __forceinline__ float bf2f(u16 u) { return (float)__builtin_bit_cast(bf16, u); }
__device__ __forceinline__ u16   f2bf(float f) { return __builtin_bit_cast(u16, (bf16)f); }
__device__ __forceinline__ u32   pkbf(float a, float b) { return (u32)f2bf(a) | ((u32)f2bf(b) << 16); }

#define NROWS 32768

// ---------- weight prep (fp32 inputs): Wexp[o][i*10 + {bw,bw,(sw*sc)[0..7]}], bf16 ----------
struct PrepArgs {
  const float* bw[7]; const float* sw[7]; const float* sc[7]; u16* wout[7];
};

template<int CIN>
__device__ __forceinline__ void prep_one(int local, const float* bw, const float* sw,
                                         const float* sc, u16* wout, int cout_real)
{
  int o = local / CIN;
  float bwf = 0.f, scf = 0.f;
  float4 s0{0,0,0,0}, s1{0,0,0,0};
  if (o < cout_real) {
    bwf = bw[local];
    scf = sc[local];
    const float4* sp = (const float4*)(sw + (size_t)local * 8);
    s0 = sp[0]; s1 = sp[1];
  }
  u16 b = f2bf(bwf);
  u32* wp = (u32*)(wout + (size_t)local * 10);
  wp[0] = (u32)b | ((u32)b << 16);
  wp[1] = pkbf(s0.x * scf, s0.y * scf);
  wp[2] = pkbf(s0.z * scf, s0.w * scf);
  wp[3] = pkbf(s1.x * scf, s1.y * scf);
  wp[4] = pkbf(s1.z * scf, s1.w * scf);
}

__global__ __launch_bounds__(256) void prep_kernel(PrepArgs pa)
{
  int tid = blockIdx.x * 256 + threadIdx.x;
  if      (tid <  32768) prep_one<128>(tid,          pa.bw[0], pa.sw[0], pa.sc[0], pa.wout[0], 256);
  else if (tid <  98304) prep_one<256>(tid -  32768, pa.bw[1], pa.sw[1], pa.sc[1], pa.wout[1], 256);
  else if (tid < 114688) prep_one<256>(tid -  98304, pa.bw[2], pa.sw[2], pa.sc[2], pa.wout[2],  64);
  else if (tid < 118784) prep_one< 64>(tid - 114688, pa.bw[3], pa.sw[3], pa.sc[3], pa.wout[3],  64);
  else if (tid < 122880) prep_one< 64>(tid - 118784, pa.bw[4], pa.sw[4], pa.sc[4], pa.wout[4],  18);
  else if (tid < 126976) prep_one< 64>(tid - 122880, pa.bw[5], pa.sw[5], pa.sc[5], pa.wout[5],  64);
  else                   prep_one< 64>(tid - 126976, pa.bw[6], pa.sw[6], pa.sc[6], pa.wout[6],   1);
}

// ---------- fused expand + MFMA GEMM layer ----------
// IN_MODE : 0 = f32, 1 = bf16
// OUT_MODE: 0 = f32 [B][COUT], 1 = bf16 [B][COUT], 2 = f32 [B][18], 3 = f32 [B]
template<int CIN, int COUT, int IN_MODE, int OUT_MODE>
__global__ __launch_bounds__(256, 2) void kan_layer(
    const void* __restrict__ hin_, const u16* __restrict__ Wexp, void* __restrict__ hout_)
{
  static_assert(CIN % 32 == 0 && COUT % 64 == 0, "tile");
  constexpr int KE   = CIN * 10;  // expanded K
  constexpr int LDWU = 164;       // LDS row stride in dwords: 160 + 4 pad
  constexpr int NT   = COUT / 64;
  __shared__ u32 Aexp[64 * LDWU];

  const int b0   = blockIdx.x * 64;
  const int tid  = threadIdx.x;
  const int wave = tid >> 6;
  const int lane = tid & 63;
  const int m    = lane & 15;
  const int quad = lane >> 4;

  const u16*   __restrict__ hb = (const u16*)hin_;
  const float* __restrict__ hf = (const float*)hin_;

  f32x4 acc[4][NT];
#pragma unroll
  for (int a = 0; a < 4; ++a)
#pragma unroll
    for (int n = 0; n < NT; ++n) acc[a][n] = (f32x4){0.f, 0.f, 0.f, 0.f};

  for (int ic = 0; ic < CIN; ic += 32) {
    // ---- expansion: 64 rows x 32 feats -> [silu_hi, silu_lo, N0..N7] ----
#pragma unroll
    for (int t = 0; t < 8; ++t) {
      int task = t * 256 + tid;
      int row  = task >> 5;
      int f    = task & 31;
      int gidx = (b0 + row) * CIN + ic + f;
      float x = (IN_MODE == 0) ? hf[gidx] : bf2f(hb[gidx]);
      // silu split hi/lo bf16 (pairs with duplicated bw slots)
      float s  = x * (1.0f / (1.0f + __expf(-x)));
      u16 uh = f2bf(s);
      u16 ul = f2bf(s - bf2f(uh));
      // uniform cubic B-spline: knot coord tp = 2.5x + 5.5, valid intervals [0,11)
      float tp = __fmaf_rn(x, 2.5f, 5.5f);
      float fi = floorf(tp);
      float uu = tp - fi;
      int   i0 = (int)fminf(fmaxf(fi, -16.f), 16.f);  // out-of-range -> all-zero bases
      float u2 = uu * uu, u3 = u2 * uu, w1 = 1.0f - uu;
      const float c6 = 0.16666666666666666f;
      float d0 = w1 * w1 * w1 * c6;                               // N_{i0-3}
      float d1 = (4.0f - 6.0f * u2 + 3.0f * u3) * c6;             // N_{i0-2}
      float d2 = (1.0f + 3.0f * uu + 3.0f * u2 - 3.0f * u3) * c6; // N_{i0-1}
      float d3 = u3 * c6;                                         // N_{i0}
      float bs[8];
#pragma unroll
      for (int g = 0; g < 8; ++g) {
        int k = g - i0 + 3;
        bs[g] = (k == 0) ? d0 : (k == 1) ? d1 : (k == 2) ? d2 : (k == 3) ? d3 : 0.f;
      }
      u32* ep = &Aexp[row * LDWU + f * 5];
      ep[0] = (u32)uh | ((u32)ul << 16);
      ep[1] = pkbf(bs[0], bs[1]);
      ep[2] = pkbf(bs[2], bs[3]);
      ep[3] = pkbf(bs[4], bs[5]);
      ep[4] = pkbf(bs[6], bs[7]);
    }
    __syncthreads();
    // ---- MFMA over this chunk's expanded K = 320 ----
#pragma unroll
    for (int ks = 0; ks < 10; ++ks) {
      bf16x8 af[4];
#pragma unroll
      for (int mt = 0; mt < 4; ++mt)
        af[mt] = *(const bf16x8*)&Aexp[(mt * 16 + m) * LDWU + ks * 16 + quad * 4];
      const int kk = ic * 10 + ks * 32 + quad * 8;
#pragma unroll
      for (int nt = 0; nt < NT; ++nt) {
        const int col = wave * (COUT / 4) + nt * 16 + m;
        bf16x8 bfr = *(const bf16x8*)(Wexp + (size_t)col * KE + kk);
#pragma unroll
        for (int mt = 0; mt < 4; ++mt)
          acc[mt][nt] = __builtin_amdgcn_mfma_f32_16x16x32_bf16(af[mt], bfr, acc[mt][nt], 0, 0, 0);
      }
    }
    __syncthreads();
  }

  // ---- epilogue: C/D layout col=lane&15, row=quad*4+r ----
  if constexpr (OUT_MODE == 0) {
    float* out = (float*)hout_;
#pragma unroll
    for (int mt = 0; mt < 4; ++mt)
#pragma unroll
      for (int nt = 0; nt < NT; ++nt)
#pragma unroll
        for (int r = 0; r < 4; ++r)
          out[(size_t)(b0 + mt * 16 + quad * 4 + r) * COUT + wave * (COUT / 4) + nt * 16 + m] = acc[mt][nt][r];
  } else if constexpr (OUT_MODE == 1) {
    u16* out = (u16*)hout_;
#pragma unroll
    for (int mt = 0; mt < 4; ++mt)
#pragma unroll
      for (int nt = 0; nt < NT; ++nt)
#pragma unroll
        for (int r = 0; r < 4; ++r)
          out[(size_t)(b0 + mt * 16 + quad * 4 + r) * COUT + wave * (COUT / 4) + nt * 16 + m] = f2bf(acc[mt][nt][r]);
  } else if constexpr (OUT_MODE == 2) {
    float* out = (float*)hout_;
    int col = wave * 16 + m;
    if (col < 18) {
#pragma unroll
      for (int mt = 0; mt < 4; ++mt)
#pragma unroll
        for (int r = 0; r < 4; ++r)
          out[(size_t)(b0 + mt * 16 + quad * 4 + r) * 18 + col] = acc[mt][0][r];
    }
  } else {
    float* out = (float*)hout_;
    if (wave == 0 && m == 0) {
#pragma unroll
      for (int mt = 0; mt < 4; ++mt)
#pragma unroll
        for (int r = 0; r < 4; ++r)
          out[b0 + mt * 16 + quad * 4 + r] = acc[mt][0][r];
    }
  }
}

extern "C" void kernel_launch(void* const* d_in, const int* in_sizes, int n_in,
                              void* d_out, int out_size, void* d_ws, size_t ws_size,
                              hipStream_t stream)
{
  (void)in_sizes; (void)n_in; (void)out_size;
  char* ws = (char*)d_ws;

  const size_t wbytes[7] = {655360u, 1310720u, 327680u, 81920u, 81920u, 81920u, 81920u};
  const bool midf32 = ws_size >= 78118912u;  // f32-intermediate plan fits?

  u16* W[7];
  char *h0, *h1, *h2;
  if (midf32) {
    h0 = ws;                       // 32768x256 f32 (32MB)
    h1 = h0 + 33554432u;           // 32768x256 f32
    h2 = h1 + 33554432u;           // 32768x64  f32 (8MB)
    size_t off = 75497472u;
    for (int l = 0; l < 7; ++l) { W[l] = (u16*)(ws + off); off += wbytes[l]; }
  } else {
    h0 = ws;                       // 32768x256 bf16 (16MB)
    h1 = h0 + 16777216u;
    h2 = h1 + 16777216u;           // 32768x64 bf16 (4MB)
    size_t off = 37748736u;
    for (int l = 0; l < 7; ++l) { W[l] = (u16*)(ws + off); off += wbytes[l]; }
  }
  char* a3 = h0;  // dead by layer 3
  char* v5 = h1;  // dead by layer 5

  PrepArgs pa;
  for (int l = 0; l < 7; ++l) {
    pa.bw[l] = (const float*)d_in[1 + 3 * l];
    pa.sw[l] = (const float*)d_in[2 + 3 * l];
    pa.sc[l] = (const float*)d_in[3 + 3 * l];
    pa.wout[l] = W[l];
  }
  prep_kernel<<<512, 256, 0, stream>>>(pa);

  dim3 g(NROWS / 64), b(256);
  float* out_adv = (float*)d_out;
  float* out_val = (float*)d_out + (size_t)NROWS * 18;
  if (midf32) {
    kan_layer<128, 256, 0, 0><<<g, b, 0, stream>>>(d_in[0], W[0], h0);
    kan_layer<256, 256, 0, 0><<<g, b, 0, stream>>>(h0, W[1], h1);
    kan_layer<256,  64, 0, 0><<<g, b, 0, stream>>>(h1, W[2], h2);
    kan_layer< 64,  64, 0, 0><<<g, b, 0, stream>>>(h2, W[3], a3);
    kan_layer< 64,  64, 0, 2><<<g, b, 0, stream>>>(a3, W[4], out_adv);
    kan_layer< 64,  64, 0, 0><<<g, b, 0, stream>>>(h2, W[5], v5);
    kan_layer< 64,  64, 0, 3><<<g, b, 0, stream>>>(v5, W[6], out_val);
  } else {
    kan_layer<128, 256, 0, 1><<<g, b, 0, stream>>>(d_in[0], W[0], h0);
    kan_layer<256, 256, 1, 1><<<g, b, 0, stream>>>(h0, W[1], h1);
    kan_layer<256,  64, 1, 1><<<g, b, 0, stream>>>(h1, W[2], h2);
    kan_layer< 64,  64, 1, 1><<<g, b, 0, stream>>>(h2, W[3], a3);
    kan_layer< 64,  64, 1, 2><<<g, b, 0, stream>>>(a3, W[4], out_adv);
    kan_layer< 64,  64, 1, 1><<<g, b, 0, stream>>>(h2, W[5], v5);
    kan_layer< 64,  64, 1, 3><<<g, b, 0, stream>>>(v5, W[6], out_val);
  }
}

// Round 4
// 374.101 us; speedup vs baseline: 1.4414x; 1.4414x over previous
//
#include <hip/hip_runtime.h>

typedef unsigned short u16;
typedef unsigned int   u32;
typedef __bf16 bf16;
typedef float f32x4  __attribute__((ext_vector_type(4)));
typedef bf16  bf16x8 __attribute__((ext_vector_type(8)));

__device__ __forceinline__ float bf2f(u16 u) { return (float)__builtin_bit_cast(bf16, u); }
__device__ __forceinline__ u16   f2bf(float f) { return __builtin_bit_cast(u16, (bf16)f); }
__device__ __forceinline__ u32   pkbf(float a, float b) { return (u32)f2bf(a) | ((u32)f2bf(b) << 16); }

#define NROWS 32768

// ---------------- expansion math (shared) ----------------
// emits 5 packed u32: [silu_hi|silu_lo, N0|N1, N2|N3, N4|N5, N6|N7]
__device__ __forceinline__ void expand_to(u32* ep, float x)
{
  float s  = x * (1.0f / (1.0f + __expf(-x)));
  u16 uh = f2bf(s);
  u16 ul = f2bf(s - bf2f(uh));
  float tp = __fmaf_rn(x, 2.5f, 5.5f);
  float fi = floorf(tp);
  float uu = tp - fi;
  int   i0 = (int)fminf(fmaxf(fi, -16.f), 16.f);   // out-of-range -> all-zero bases
  float u2 = uu * uu, u3 = u2 * uu, w1 = 1.0f - uu;
  const float c6 = 0.16666666666666666f;
  float d0 = w1 * w1 * w1 * c6;
  float d1 = (4.0f - 6.0f * u2 + 3.0f * u3) * c6;
  float d2 = (1.0f + 3.0f * uu + 3.0f * u2 - 3.0f * u3) * c6;
  float d3 = u3 * c6;
  float bs[8];
#pragma unroll
  for (int g = 0; g < 8; ++g) {
    int k = g - i0 + 3;
    bs[g] = (k == 0) ? d0 : (k == 1) ? d1 : (k == 2) ? d2 : (k == 3) ? d3 : 0.f;
  }
  ep[0] = (u32)uh | ((u32)ul << 16);
  ep[1] = pkbf(bs[0], bs[1]);
  ep[2] = pkbf(bs[2], bs[3]);
  ep[3] = pkbf(bs[4], bs[5]);
  ep[4] = pkbf(bs[6], bs[7]);
}

// ---------------- weight prep: B pre-swizzled into MFMA fragment order ----------------
// element (o, ke) -> wout[ ((ke>>5)*ntiles + (o>>4))*64 + ((ke>>3)&3)*16 + (o&15) ]*8 + (ke&7)
struct PrepArgs {
  const float* bw[7]; const float* sw[7]; const float* sc[7]; u16* wout[7];
};

template<int CIN>
__device__ __forceinline__ void prep_one(int local, const float* bw, const float* sw,
                                         const float* sc, u16* wout, int cout_real, int ntiles)
{
  int o = local / CIN;
  int i = local - o * CIN;
  float bwf = 0.f, scf = 0.f;
  float4 s0{0,0,0,0}, s1{0,0,0,0};
  if (o < cout_real) {
    bwf = bw[local];
    scf = sc[local];
    const float4* sp = (const float4*)(sw + (size_t)local * 8);
    s0 = sp[0]; s1 = sp[1];
  }
  u16 raw[10];
  raw[0] = raw[1] = f2bf(bwf);
  raw[2] = f2bf(s0.x * scf); raw[3] = f2bf(s0.y * scf);
  raw[4] = f2bf(s0.z * scf); raw[5] = f2bf(s0.w * scf);
  raw[6] = f2bf(s1.x * scf); raw[7] = f2bf(s1.y * scf);
  raw[8] = f2bf(s1.z * scf); raw[9] = f2bf(s1.w * scf);
  int ntg = o >> 4, n15 = o & 15;
#pragma unroll
  for (int s = 0; s < 10; ++s) {
    int ke = i * 10 + s;
    size_t idx = (((size_t)(ke >> 5) * ntiles + ntg) * 64 + ((ke >> 3) & 3) * 16 + n15) * 8 + (ke & 7);
    wout[idx] = raw[s];
  }
}

__global__ __launch_bounds__(256) void prep_kernel(PrepArgs pa)
{
  int tid = blockIdx.x * 256 + threadIdx.x;
  if      (tid <  32768) prep_one<128>(tid,          pa.bw[0], pa.sw[0], pa.sc[0], pa.wout[0], 256, 16);
  else if (tid <  98304) prep_one<256>(tid -  32768, pa.bw[1], pa.sw[1], pa.sc[1], pa.wout[1], 256, 16);
  else if (tid < 114688) prep_one<256>(tid -  98304, pa.bw[2], pa.sw[2], pa.sc[2], pa.wout[2],  64,  4);
  else if (tid < 118784) prep_one< 64>(tid - 114688, pa.bw[3], pa.sw[3], pa.sc[3], pa.wout[3],  64,  4);
  else if (tid < 122880) prep_one< 64>(tid - 118784, pa.bw[4], pa.sw[4], pa.sc[4], pa.wout[4],  18,  4);
  else if (tid < 126976) prep_one< 64>(tid - 122880, pa.bw[5], pa.sw[5], pa.sc[5], pa.wout[5],  64,  4);
  else                   prep_one< 64>(tid - 126976, pa.bw[6], pa.sw[6], pa.sc[6], pa.wout[6],   1,  4);
}

// ---------------- fused expand + MFMA GEMM layer (512 thr, 8 waves = 2 rg x 4 cg) ----------------
// IN_MODE: 0 = f32, 1 = bf16   OUT_MODE: 0 = f32 [B][COUT], 1 = bf16 [B][COUT]
template<int CIN, int COUT, int IN_MODE, int OUT_MODE>
__global__ __launch_bounds__(512, 4) void kan_layer(
    const void* __restrict__ hin_, const u16* __restrict__ W, void* __restrict__ hout_)
{
  static_assert(CIN % 32 == 0 && COUT % 64 == 0, "tile");
  constexpr int LDWU   = 164;        // LDS row stride in dwords (160 data + 4 pad)
  constexpr int NT     = COUT / 64;  // 16-col tiles per col-group
  constexpr int NTILES = COUT / 16;
  __shared__ u32 Aexp[64 * LDWU];

  const int b0   = blockIdx.x * 64;
  const int tid  = threadIdx.x;
  const int wave = tid >> 6;
  const int lane = tid & 63;
  const int m    = lane & 15;
  const int quad = lane >> 4;
  const int rg   = wave >> 2;   // row group (0..1): rows rg*32 + mt*16
  const int cg   = wave & 3;    // col group (0..3): cols cg*16*NT + nt*16 + m

  const u16*   __restrict__ hb = (const u16*)hin_;
  const float* __restrict__ hf = (const float*)hin_;

  f32x4 acc[2][NT];
#pragma unroll
  for (int a = 0; a < 2; ++a)
#pragma unroll
    for (int n = 0; n < NT; ++n) acc[a][n] = (f32x4){0.f, 0.f, 0.f, 0.f};

  for (int ic = 0; ic < CIN; ic += 32) {
#pragma unroll
    for (int t = 0; t < 4; ++t) {                 // 2048 tasks / 512 threads
      int task = t * 512 + tid;
      int row  = task >> 5;
      int f    = task & 31;
      int gidx = (b0 + row) * CIN + ic + f;
      float x = (IN_MODE == 0) ? hf[gidx] : bf2f(hb[gidx]);
      expand_to(&Aexp[row * LDWU + f * 5], x);
    }
    __syncthreads();
    const int kcb = (ic >> 5) * 10;
#pragma unroll
    for (int ks = 0; ks < 10; ++ks) {
      bf16x8 af[2];
#pragma unroll
      for (int mt = 0; mt < 2; ++mt)
        af[mt] = *(const bf16x8*)&Aexp[(rg * 32 + mt * 16 + m) * LDWU + ks * 16 + quad * 4];
#pragma unroll
      for (int nt = 0; nt < NT; ++nt) {
        bf16x8 bfr = *(const bf16x8*)(W + (((size_t)(kcb + ks) * NTILES + cg * NT + nt) * 64 + lane) * 8);
#pragma unroll
        for (int mt = 0; mt < 2; ++mt)
          acc[mt][nt] = __builtin_amdgcn_mfma_f32_16x16x32_bf16(af[mt], bfr, acc[mt][nt], 0, 0, 0);
      }
    }
    __syncthreads();
  }

  // epilogue: C/D col=lane&15, row=quad*4+r
#pragma unroll
  for (int mt = 0; mt < 2; ++mt)
#pragma unroll
    for (int nt = 0; nt < NT; ++nt)
#pragma unroll
      for (int r = 0; r < 4; ++r) {
        size_t off = (size_t)(b0 + rg * 32 + mt * 16 + quad * 4 + r) * COUT + cg * 16 * NT + nt * 16 + m;
        if constexpr (OUT_MODE == 0) ((float*)hout_)[off] = acc[mt][nt][r];
        else                         ((u16*)hout_)[off]   = f2bf(acc[mt][nt][r]);
      }
}

// ---------------- fused tail: h2 -> {L3 -> L4 -> adv , L5 -> L6 -> val} ----------------
template<int IN_MODE>
__global__ __launch_bounds__(512, 4) void tail_kernel(
    const void* __restrict__ h2_, const u16* __restrict__ W3, const u16* __restrict__ W4,
    const u16* __restrict__ W5, const u16* __restrict__ W6,
    float* __restrict__ out_adv, float* __restrict__ out_val)
{
  constexpr int LDWT = 84;   // 16 feats * 5 dw + 4 pad
  __shared__ u32   Aexp[64 * LDWT];   // 21504 B
  __shared__ float hA[64 * 65];       // 16640 B (a3 tile, f32)
  __shared__ float hV[64 * 65];       // 16640 B (v5 tile, f32)

  const int b0   = blockIdx.x * 64;
  const int tid  = threadIdx.x;
  const int wave = tid >> 6;
  const int lane = tid & 63;
  const int m    = lane & 15;
  const int quad = lane >> 4;
  const int rg   = wave >> 2;
  const int cg   = wave & 3;

  const u16*   __restrict__ hb = (const u16*)h2_;
  const float* __restrict__ hf = (const float*)h2_;

  // ---- phase A: expand h2 once, accumulate L3 and L5 together ----
  f32x4 a3[2], a5[2];
#pragma unroll
  for (int mt = 0; mt < 2; ++mt) { a3[mt] = (f32x4){0,0,0,0}; a5[mt] = (f32x4){0,0,0,0}; }

  for (int ic = 0; ic < 64; ic += 16) {
#pragma unroll
    for (int t = 0; t < 2; ++t) {                 // 1024 tasks / 512 threads
      int task = t * 512 + tid;
      int row  = task >> 4;
      int f    = task & 15;
      int gidx = (b0 + row) * 64 + ic + f;
      float x = (IN_MODE == 0) ? hf[gidx] : bf2f(hb[gidx]);
      expand_to(&Aexp[row * LDWT + f * 5], x);
    }
    __syncthreads();
    const int kcb = (ic >> 4) * 5;
#pragma unroll
    for (int ks = 0; ks < 5; ++ks) {
      bf16x8 af[2];
#pragma unroll
      for (int mt = 0; mt < 2; ++mt)
        af[mt] = *(const bf16x8*)&Aexp[(rg * 32 + mt * 16 + m) * LDWT + ks * 16 + quad * 4];
      size_t bidx = (((size_t)(kcb + ks) * 4 + cg) * 64 + lane) * 8;
      bf16x8 b3 = *(const bf16x8*)(W3 + bidx);
      bf16x8 b5 = *(const bf16x8*)(W5 + bidx);
#pragma unroll
      for (int mt = 0; mt < 2; ++mt) {
        a3[mt] = __builtin_amdgcn_mfma_f32_16x16x32_bf16(af[mt], b3, a3[mt], 0, 0, 0);
        a5[mt] = __builtin_amdgcn_mfma_f32_16x16x32_bf16(af[mt], b5, a5[mt], 0, 0, 0);
      }
    }
    __syncthreads();
  }
#pragma unroll
  for (int mt = 0; mt < 2; ++mt)
#pragma unroll
    for (int r = 0; r < 4; ++r) {
      int row = rg * 32 + mt * 16 + quad * 4 + r;
      hA[row * 65 + cg * 16 + m] = a3[mt][r];
      hV[row * 65 + cg * 16 + m] = a5[mt][r];
    }
  __syncthreads();

  // ---- phase B1: a3 -> L4 -> advantage (cols < 18) ----
  f32x4 a4[2];
#pragma unroll
  for (int mt = 0; mt < 2; ++mt) a4[mt] = (f32x4){0,0,0,0};
  for (int ic = 0; ic < 64; ic += 16) {
#pragma unroll
    for (int t = 0; t < 2; ++t) {
      int task = t * 512 + tid;
      int row  = task >> 4;
      int f    = task & 15;
      expand_to(&Aexp[row * LDWT + f * 5], hA[row * 65 + ic + f]);
    }
    __syncthreads();
    const int kcb = (ic >> 4) * 5;
#pragma unroll
    for (int ks = 0; ks < 5; ++ks) {
      bf16x8 af[2];
#pragma unroll
      for (int mt = 0; mt < 2; ++mt)
        af[mt] = *(const bf16x8*)&Aexp[(rg * 32 + mt * 16 + m) * LDWT + ks * 16 + quad * 4];
      bf16x8 b4 = *(const bf16x8*)(W4 + (((size_t)(kcb + ks) * 4 + cg) * 64 + lane) * 8);
#pragma unroll
      for (int mt = 0; mt < 2; ++mt)
        a4[mt] = __builtin_amdgcn_mfma_f32_16x16x32_bf16(af[mt], b4, a4[mt], 0, 0, 0);
    }
    __syncthreads();
  }
  {
    int col = cg * 16 + m;
    if (col < 18) {
#pragma unroll
      for (int mt = 0; mt < 2; ++mt)
#pragma unroll
        for (int r = 0; r < 4; ++r)
          out_adv[(size_t)(b0 + rg * 32 + mt * 16 + quad * 4 + r) * 18 + col] = a4[mt][r];
    }
  }

  // ---- phase B2: v5 -> L6 -> state value (col 0) ----
  f32x4 a6[2];
#pragma unroll
  for (int mt = 0; mt < 2; ++mt) a6[mt] = (f32x4){0,0,0,0};
  for (int ic = 0; ic < 64; ic += 16) {
#pragma unroll
    for (int t = 0; t < 2; ++t) {
      int task = t * 512 + tid;
      int row  = task >> 4;
      int f    = task & 15;
      expand_to(&Aexp[row * LDWT + f * 5], hV[row * 65 + ic + f]);
    }
    __syncthreads();
    const int kcb = (ic >> 4) * 5;
#pragma unroll
    for (int ks = 0; ks < 5; ++ks) {
      bf16x8 af[2];
#pragma unroll
      for (int mt = 0; mt < 2; ++mt)
        af[mt] = *(const bf16x8*)&Aexp[(rg * 32 + mt * 16 + m) * LDWT + ks * 16 + quad * 4];
      bf16x8 b6 = *(const bf16x8*)(W6 + (((size_t)(kcb + ks) * 4 + cg) * 64 + lane) * 8);
#pragma unroll
      for (int mt = 0; mt < 2; ++mt)
        a6[mt] = __builtin_amdgcn_mfma_f32_16x16x32_bf16(af[mt], b6, a6[mt], 0, 0, 0);
    }
    __syncthreads();
  }
  if (cg == 0 && m == 0) {
#pragma unroll
    for (int mt = 0; mt < 2; ++mt)
#pragma unroll
      for (int r = 0; r < 4; ++r)
        out_val[b0 + rg * 32 + mt * 16 + quad * 4 + r] = a6[mt][r];
  }
}

extern "C" void kernel_launch(void* const* d_in, const int* in_sizes, int n_in,
                              void* d_out, int out_size, void* d_ws, size_t ws_size,
                              hipStream_t stream)
{
  (void)in_sizes; (void)n_in; (void)out_size;
  char* ws = (char*)d_ws;

  const size_t wbytes[7] = {655360u, 1310720u, 327680u, 81920u, 81920u, 81920u, 81920u};
  const bool midf32 = ws_size >= 78118912u;

  u16* W[7];
  char *h0, *h1, *h2;
  if (midf32) {
    h0 = ws;                       // 32768x256 f32
    h1 = h0 + 33554432u;
    h2 = h1 + 33554432u;           // 32768x64 f32
    size_t off = 75497472u;
    for (int l = 0; l < 7; ++l) { W[l] = (u16*)(ws + off); off += wbytes[l]; }
  } else {
    h0 = ws;                       // 32768x256 bf16
    h1 = h0 + 16777216u;
    h2 = h1 + 16777216u;           // 32768x64 bf16
    size_t off = 37748736u;
    for (int l = 0; l < 7; ++l) { W[l] = (u16*)(ws + off); off += wbytes[l]; }
  }

  PrepArgs pa;
  for (int l = 0; l < 7; ++l) {
    pa.bw[l] = (const float*)d_in[1 + 3 * l];
    pa.sw[l] = (const float*)d_in[2 + 3 * l];
    pa.sc[l] = (const float*)d_in[3 + 3 * l];
    pa.wout[l] = W[l];
  }
  prep_kernel<<<512, 256, 0, stream>>>(pa);

  dim3 g(NROWS / 64), b(512);
  float* out_adv = (float*)d_out;
  float* out_val = (float*)d_out + (size_t)NROWS * 18;
  if (midf32) {
    kan_layer<128, 256, 0, 0><<<g, b, 0, stream>>>(d_in[0], W[0], h0);
    kan_layer<256, 256, 0, 0><<<g, b, 0, stream>>>(h0, W[1], h1);
    kan_layer<256,  64, 0, 0><<<g, b, 0, stream>>>(h1, W[2], h2);
    tail_kernel<0><<<g, b, 0, stream>>>(h2, W[3], W[4], W[5], W[6], out_adv, out_val);
  } else {
    kan_layer<128, 256, 0, 1><<<g, b, 0, stream>>>(d_in[0], W[0], h0);
    kan_layer<256, 256, 1, 1><<<g, b, 0, stream>>>(h0, W[1], h1);
    kan_layer<256,  64, 1, 1><<<g, b, 0, stream>>>(h1, W[2], h2);
    tail_kernel<1><<<g, b, 0, stream>>>(h2, W[3], W[4], W[5], W[6], out_adv, out_val);
  }
}

// Round 5
// 369.001 us; speedup vs baseline: 1.4613x; 1.0138x over previous
//
#include <hip/hip_runtime.h>

typedef unsigned short u16;
typedef unsigned int   u32;
typedef __bf16 bf16;
typedef float f32x4  __attribute__((ext_vector_type(4)));
typedef bf16  bf16x8 __attribute__((ext_vector_type(8)));

__device__ __forceinline__ float bf2f(u16 u){ return (float)__builtin_bit_cast(bf16,u); }
__device__ __forceinline__ u16   f2bf(float f){ return __builtin_bit_cast(u16,(bf16)f); }
__device__ __forceinline__ u32   pkbf(float a,float b){ return (u32)f2bf(a)|((u32)f2bf(b)<<16); }

#define NROWS 32768

// ---- expansion: x -> packed silu hi/lo pair + 8 basis bf16 (uint4) ----
__device__ __forceinline__ void expand_vals(float x, u32& spk, uint4& bpk)
{
  float s = x * (1.0f/(1.0f+__expf(-x)));
  u16 uh = f2bf(s);
  u16 ul = f2bf(s - bf2f(uh));
  spk = (u32)uh | ((u32)ul<<16);
  float tp = __fmaf_rn(x, 2.5f, 5.5f);
  float fi = floorf(tp);
  float uu = tp - fi;
  int i0 = (int)fminf(fmaxf(fi,-16.f),16.f);   // out-of-range -> all-zero bases
  float u2=uu*uu, u3=u2*uu, w1=1.0f-uu;
  const float c6 = 0.16666666666666666f;
  float d0 = w1*w1*w1*c6;
  float d1 = (4.0f-6.0f*u2+3.0f*u3)*c6;
  float d2 = (1.0f+3.0f*uu+3.0f*u2-3.0f*u3)*c6;
  float d3 = u3*c6;
  float bs[8];
#pragma unroll
  for (int g=0; g<8; ++g){
    int k = g - i0 + 3;
    bs[g] = (k==0)?d0:(k==1)?d1:(k==2)?d2:(k==3)?d3:0.f;
  }
  bpk.x = pkbf(bs[0],bs[1]); bpk.y = pkbf(bs[2],bs[3]);
  bpk.z = pkbf(bs[4],bs[5]); bpk.w = pkbf(bs[6],bs[7]);
}

// ---------------- destination-major weight prep ----------------
// KE order per chunk (CF feats): [2*CF silu slots | 8*CF basis slots]
// dest layout: ((kstep*NTILES + ntile)*64 + lane)*8 + j ; lane=(kpos>>3)*16+(o&15), kpos=k within 32
struct PrepArgs {
  const float* bw[7]; const float* sw[7]; const float* sc[7];
  u16* w[7];
  int cin[7]; int coutr[7]; int ntsh[7]; int cf[7]; int ksc[7]; int silks[7];
  u32 elems[7];
};

__global__ __launch_bounds__(256) void prep_kernel(PrepArgs pa)
{
  u32 idx = blockIdx.x*256 + threadIdx.x;
  int L = 0;
  u32 off = idx;
  while (L < 6 && off >= pa.elems[L]) { off -= pa.elems[L]; ++L; }
  int j    = off & 7;
  int lane = (off>>3) & 63;
  u32 tl   = off >> 9;
  int ntsh = pa.ntsh[L];
  u32 kstep = tl >> ntsh;
  int ntile = (int)(tl & ((1u<<ntsh)-1u));
  int o    = ntile*16 + (lane&15);
  int kpos = (lane>>4)*8 + j;
  int KSC = pa.ksc[L], CF = pa.cf[L], SK = pa.silks[L];
  u32 c = kstep / (u32)KSC;
  int r = (int)(kstep - c*(u32)KSC);
  int i, g; bool sil;
  if (r < SK){ int kl = r*32 + kpos;      i = (int)c*CF + (kl>>1); g = 0;     sil = true;  }
  else       { int kl = (r-SK)*32 + kpos; i = (int)c*CF + (kl>>3); g = kl&7;  sil = false; }
  float v = 0.f;
  if (o < pa.coutr[L]) {
    size_t e = (size_t)o*pa.cin[L] + i;
    v = sil ? pa.bw[L][e] : pa.sw[L][e*8+g]*pa.sc[L][e];
  }
  pa.w[L][off] = f2bf(v);
}

// ---------------- fused expand + MFMA layer (512 thr = 2 rg x 4 cg) ----------------
// IN_MODE: 0=f32, 1=bf16   OUT_MODE: 0=f32 [B][COUT], 1=bf16 [B][COUT]
template<int CIN,int COUT,int IN_MODE,int OUT_MODE>
__global__ __launch_bounds__(512,4) void kan_layer(const void* __restrict__ hin_,
    const u16* __restrict__ W, void* __restrict__ hout_)
{
  constexpr int NC=CIN/32, TOTK=NC*10;
  constexpr int NT=COUT/64, NTILES=COUT/16;
  constexpr int DEPTH = (NT==1)?4:2;          // B-prefetch pipeline depth
  constexpr int SROW=36, BROW=132, BOFF=64*36;   // dwords
  __shared__ u32 Aexp[BOFF + 64*BROW];           // 43008 B

  const int b0 = blockIdx.x*64;
  const int tid = threadIdx.x;
  const int wave = tid>>6, lane = tid&63, m = lane&15, quad = lane>>4;
  const int rg = wave>>2, cg = wave&3;

  const u16*   __restrict__ hb = (const u16*)hin_;
  const float* __restrict__ hf = (const float*)hin_;

  f32x4 acc[2][NT];
#pragma unroll
  for (int a=0;a<2;++a)
#pragma unroll
    for (int n=0;n<NT;++n) acc[a][n] = (f32x4){0.f,0.f,0.f,0.f};

  bf16x8 bbuf[DEPTH][NT];
  auto loadB = [&](int kstep, bf16x8* dst){
    if (kstep < TOTK){
#pragma unroll
      for (int nt=0; nt<NT; ++nt)
        dst[nt] = *(const bf16x8*)(W + (((size_t)kstep*NTILES + cg*NT+nt)*64 + lane)*8);
    }
  };
#pragma unroll
  for (int d=0; d<DEPTH-1; ++d) loadB(d, bbuf[d]);

  float xb[2][4];
  auto loadX = [&](int kc, float* dst){
#pragma unroll
    for (int t=0;t<4;++t){
      int task = t*512+tid, row = task>>5, f = task&31;
      int gi = (b0+row)*CIN + kc*32 + f;
      dst[t] = (IN_MODE==0)? hf[gi] : bf2f(hb[gi]);
    }
  };
  loadX(0, xb[0]);

  for (int kc=0; kc<NC; ++kc){
    const float* xc = xb[kc&1];
#pragma unroll
    for (int t=0;t<4;++t){
      int task=t*512+tid, row=task>>5, f=task&31;
      u32 spk; uint4 bpk;
      expand_vals(xc[t], spk, bpk);
      Aexp[row*SROW + f] = spk;
      *(uint4*)&Aexp[BOFF + row*BROW + f*4] = bpk;
    }
    if (kc+1 < NC) loadX(kc+1, xb[(kc+1)&1]);
    __syncthreads();
#pragma unroll
    for (int ks=0; ks<10; ++ks){
      const int kstep = kc*10 + ks;
      loadB(kstep + DEPTH-1, bbuf[DEPTH-1]);
      bf16x8 af[2];
#pragma unroll
      for (int mt=0; mt<2; ++mt){
        int row = rg*32 + mt*16 + m;
        af[mt] = (ks<2)
          ? *(const bf16x8*)&Aexp[row*SROW + ks*16 + quad*4]
          : *(const bf16x8*)&Aexp[BOFF + row*BROW + (ks-2)*16 + quad*4];
      }
#pragma unroll
      for (int nt=0; nt<NT; ++nt)
#pragma unroll
        for (int mt=0; mt<2; ++mt)
          acc[mt][nt] = __builtin_amdgcn_mfma_f32_16x16x32_bf16(af[mt], bbuf[0][nt], acc[mt][nt],0,0,0);
#pragma unroll
      for (int d=0; d<DEPTH-1; ++d)
#pragma unroll
        for (int nt=0; nt<NT; ++nt) bbuf[d][nt] = bbuf[d+1][nt];
    }
    __syncthreads();
  }

  // epilogue: C/D col=lane&15, row=quad*4+r
#pragma unroll
  for (int mt=0; mt<2; ++mt)
#pragma unroll
    for (int nt=0; nt<NT; ++nt)
#pragma unroll
      for (int r=0; r<4; ++r){
        size_t off = (size_t)(b0 + rg*32 + mt*16 + quad*4 + r)*COUT + cg*16*NT + nt*16 + m;
        if constexpr (OUT_MODE==0) ((float*)hout_)[off] = acc[mt][nt][r];
        else                       ((u16*)hout_)[off]   = f2bf(acc[mt][nt][r]);
      }
}

// ---------------- fused tail: h2 -> {L3->L4->adv , L5->L6->val} ----------------
template<int IN_MODE>
__global__ __launch_bounds__(512,4) void tail_kernel(const void* __restrict__ h2_,
  const u16* __restrict__ W3, const u16* __restrict__ W4,
  const u16* __restrict__ W5, const u16* __restrict__ W6,
  float* __restrict__ out_adv, float* __restrict__ out_val)
{
  constexpr int SROW=20, BROW=68, BOFF=64*20;    // dwords (CF=16 chunks)
  __shared__ u32   Aexp[BOFF + 64*BROW];         // 22528 B
  __shared__ float hA[64*65], hV[64*65];         // 2 x 16640 B

  const int b0 = blockIdx.x*64;
  const int tid = threadIdx.x;
  const int wave = tid>>6, lane = tid&63, m = lane&15, quad = lane>>4;
  const int rg = wave>>2, cg = wave&3;

  const u16*   __restrict__ hb = (const u16*)h2_;
  const float* __restrict__ hf = (const float*)h2_;

  // ---- phase A: expand h2 once, accumulate L3 & L5 ----
  f32x4 a3[2], a5[2];
#pragma unroll
  for (int mt=0;mt<2;++mt){ a3[mt]=(f32x4){0,0,0,0}; a5[mt]=(f32x4){0,0,0,0}; }

  bf16x8 w3b[3], w5b[3];
  auto loadB2 = [&](int kstep, int d){
    if (kstep < 20){
      size_t bi = (((size_t)kstep*4 + cg)*64 + lane)*8;
      w3b[d] = *(const bf16x8*)(W3+bi);
      w5b[d] = *(const bf16x8*)(W5+bi);
    }
  };
  loadB2(0,0); loadB2(1,1);

  float xb[2][2];
  auto loadX = [&](int kc, float* dst){
#pragma unroll
    for (int t=0;t<2;++t){
      int task = t*512+tid, row=task>>4, f=task&15;
      int gi = (b0+row)*64 + kc*16 + f;
      dst[t] = (IN_MODE==0)? hf[gi] : bf2f(hb[gi]);
    }
  };
  loadX(0, xb[0]);

  for (int kc=0; kc<4; ++kc){
    const float* xc = xb[kc&1];
#pragma unroll
    for (int t=0;t<2;++t){
      int task=t*512+tid, row=task>>4, f=task&15;
      u32 spk; uint4 bpk;
      expand_vals(xc[t], spk, bpk);
      Aexp[row*SROW + f] = spk;
      *(uint4*)&Aexp[BOFF + row*BROW + f*4] = bpk;
    }
    if (kc+1 < 4) loadX(kc+1, xb[(kc+1)&1]);
    __syncthreads();
#pragma unroll
    for (int ks=0; ks<5; ++ks){
      const int kstep = kc*5 + ks;
      loadB2(kstep+2, 2);
      bf16x8 af[2];
#pragma unroll
      for (int mt=0; mt<2; ++mt){
        int row = rg*32 + mt*16 + m;
        af[mt] = (ks<1)
          ? *(const bf16x8*)&Aexp[row*SROW + quad*4]
          : *(const bf16x8*)&Aexp[BOFF + row*BROW + (ks-1)*16 + quad*4];
      }
#pragma unroll
      for (int mt=0; mt<2; ++mt){
        a3[mt] = __builtin_amdgcn_mfma_f32_16x16x32_bf16(af[mt], w3b[0], a3[mt],0,0,0);
        a5[mt] = __builtin_amdgcn_mfma_f32_16x16x32_bf16(af[mt], w5b[0], a5[mt],0,0,0);
      }
      w3b[0]=w3b[1]; w3b[1]=w3b[2]; w5b[0]=w5b[1]; w5b[1]=w5b[2];
    }
    __syncthreads();
  }
#pragma unroll
  for (int mt=0;mt<2;++mt)
#pragma unroll
    for (int r=0;r<4;++r){
      int row = rg*32 + mt*16 + quad*4 + r;
      hA[row*65 + cg*16 + m] = a3[mt][r];
      hV[row*65 + cg*16 + m] = a5[mt][r];
    }
  __syncthreads();

  // ---- phase B1: a3 -> L4 -> advantage ----
  f32x4 a4[2];
#pragma unroll
  for (int mt=0;mt<2;++mt) a4[mt]=(f32x4){0,0,0,0};
  bf16x8 w4b[3];
  auto loadB4 = [&](int kstep, int d){
    if (kstep < 20) w4b[d] = *(const bf16x8*)(W4 + (((size_t)kstep*4 + cg)*64 + lane)*8);
  };
  loadB4(0,0); loadB4(1,1);
  for (int kc=0; kc<4; ++kc){
#pragma unroll
    for (int t=0;t<2;++t){
      int task=t*512+tid, row=task>>4, f=task&15;
      u32 spk; uint4 bpk;
      expand_vals(hA[row*65 + kc*16 + f], spk, bpk);
      Aexp[row*SROW + f] = spk;
      *(uint4*)&Aexp[BOFF + row*BROW + f*4] = bpk;
    }
    __syncthreads();
#pragma unroll
    for (int ks=0; ks<5; ++ks){
      loadB4(kc*5+ks+2, 2);
      bf16x8 af[2];
#pragma unroll
      for (int mt=0; mt<2; ++mt){
        int row = rg*32 + mt*16 + m;
        af[mt] = (ks<1)
          ? *(const bf16x8*)&Aexp[row*SROW + quad*4]
          : *(const bf16x8*)&Aexp[BOFF + row*BROW + (ks-1)*16 + quad*4];
      }
#pragma unroll
      for (int mt=0; mt<2; ++mt)
        a4[mt] = __builtin_amdgcn_mfma_f32_16x16x32_bf16(af[mt], w4b[0], a4[mt],0,0,0);
      w4b[0]=w4b[1]; w4b[1]=w4b[2];
    }
    __syncthreads();
  }
  {
    int col = cg*16 + m;
    if (col < 18){
#pragma unroll
      for (int mt=0;mt<2;++mt)
#pragma unroll
        for (int r=0;r<4;++r)
          out_adv[(size_t)(b0 + rg*32 + mt*16 + quad*4 + r)*18 + col] = a4[mt][r];
    }
  }

  // ---- phase B2: v5 -> L6 -> value ----
  f32x4 a6[2];
#pragma unroll
  for (int mt=0;mt<2;++mt) a6[mt]=(f32x4){0,0,0,0};
  bf16x8 w6b[3];
  auto loadB6 = [&](int kstep, int d){
    if (kstep < 20) w6b[d] = *(const bf16x8*)(W6 + (((size_t)kstep*4 + cg)*64 + lane)*8);
  };
  loadB6(0,0); loadB6(1,1);
  for (int kc=0; kc<4; ++kc){
#pragma unroll
    for (int t=0;t<2;++t){
      int task=t*512+tid, row=task>>4, f=task&15;
      u32 spk; uint4 bpk;
      expand_vals(hV[row*65 + kc*16 + f], spk, bpk);
      Aexp[row*SROW + f] = spk;
      *(uint4*)&Aexp[BOFF + row*BROW + f*4] = bpk;
    }
    __syncthreads();
#pragma unroll
    for (int ks=0; ks<5; ++ks){
      loadB6(kc*5+ks+2, 2);
      bf16x8 af[2];
#pragma unroll
      for (int mt=0; mt<2; ++mt){
        int row = rg*32 + mt*16 + m;
        af[mt] = (ks<1)
          ? *(const bf16x8*)&Aexp[row*SROW + quad*4]
          : *(const bf16x8*)&Aexp[BOFF + row*BROW + (ks-1)*16 + quad*4];
      }
#pragma unroll
      for (int mt=0; mt<2; ++mt)
        a6[mt] = __builtin_amdgcn_mfma_f32_16x16x32_bf16(af[mt], w6b[0], a6[mt],0,0,0);
      w6b[0]=w6b[1]; w6b[1]=w6b[2];
    }
    __syncthreads();
  }
  if (cg==0 && m==0){
#pragma unroll
    for (int mt=0;mt<2;++mt)
#pragma unroll
      for (int r=0;r<4;++r)
        out_val[b0 + rg*32 + mt*16 + quad*4 + r] = a6[mt][r];
  }
}

extern "C" void kernel_launch(void* const* d_in, const int* in_sizes, int n_in,
                              void* d_out, int out_size, void* d_ws, size_t ws_size,
                              hipStream_t stream)
{
  (void)in_sizes; (void)n_in; (void)out_size;
  char* ws = (char*)d_ws;

  const size_t wbytes[7] = {655360u, 1310720u, 327680u, 81920u, 81920u, 81920u, 81920u};
  const bool midf32 = ws_size >= 78118912u;

  u16* W[7];
  char *h0, *h1, *h2;
  if (midf32) {
    h0 = ws;                       // 32768x256 f32
    h1 = h0 + 33554432u;
    h2 = h1 + 33554432u;           // 32768x64 f32
    size_t off = 75497472u;
    for (int l=0;l<7;++l){ W[l] = (u16*)(ws+off); off += wbytes[l]; }
  } else {
    h0 = ws;                       // bf16 fallback
    h1 = h0 + 16777216u;
    h2 = h1 + 16777216u;
    size_t off = 37748736u;
    for (int l=0;l<7;++l){ W[l] = (u16*)(ws+off); off += wbytes[l]; }
  }

  PrepArgs pa;
  const int cins[7]   = {128,256,256,64,64,64,64};
  const int coutr[7]  = {256,256,64,64,18,64,1};
  const int ntsh[7]   = {4,4,2,2,2,2,2};
  const int cfs[7]    = {32,32,32,16,16,16,16};
  const int kscs[7]   = {10,10,10,5,5,5,5};
  const int silks[7]  = {2,2,2,1,1,1,1};
  const u32 elems[7]  = {327680u,655360u,163840u,40960u,40960u,40960u,40960u};
  for (int l=0;l<7;++l){
    pa.bw[l] = (const float*)d_in[1+3*l];
    pa.sw[l] = (const float*)d_in[2+3*l];
    pa.sc[l] = (const float*)d_in[3+3*l];
    pa.w[l]  = W[l];
    pa.cin[l]=cins[l]; pa.coutr[l]=coutr[l]; pa.ntsh[l]=ntsh[l];
    pa.cf[l]=cfs[l]; pa.ksc[l]=kscs[l]; pa.silks[l]=silks[l]; pa.elems[l]=elems[l];
  }
  prep_kernel<<<5120, 256, 0, stream>>>(pa);

  dim3 g(NROWS/64), b(512);
  float* out_adv = (float*)d_out;
  float* out_val = (float*)d_out + (size_t)NROWS*18;
  if (midf32) {
    kan_layer<128,256,0,0><<<g,b,0,stream>>>(d_in[0], W[0], h0);
    kan_layer<256,256,0,0><<<g,b,0,stream>>>(h0, W[1], h1);
    kan_layer<256, 64,0,0><<<g,b,0,stream>>>(h1, W[2], h2);
    tail_kernel<0><<<g,b,0,stream>>>(h2, W[3], W[4], W[5], W[6], out_adv, out_val);
  } else {
    kan_layer<128,256,0,1><<<g,b,0,stream>>>(d_in[0], W[0], h0);
    kan_layer<256,256,1,1><<<g,b,0,stream>>>(h0, W[1], h1);
    kan_layer<256, 64,1,1><<<g,b,0,stream>>>(h1, W[2], h2);
    tail_kernel<1><<<g,b,0,stream>>>(h2, W[3], W[4], W[5], W[6], out_adv, out_val);
  }
}

// Round 6
// 238.716 us; speedup vs baseline: 2.2589x; 1.5458x over previous
//
#include <hip/hip_runtime.h>

typedef unsigned short u16;
typedef unsigned int   u32;
typedef unsigned long long u64;
typedef __bf16 bf16;
typedef float f32x4  __attribute__((ext_vector_type(4)));
typedef bf16  bf16x8 __attribute__((ext_vector_type(8)));

__device__ __forceinline__ float bf2f(u16 u){ return (float)__builtin_bit_cast(bf16,u); }
__device__ __forceinline__ u16   f2bf(float f){ return __builtin_bit_cast(u16,(bf16)f); }
__device__ __forceinline__ u32   pkbf(float a,float b){ return (u32)f2bf(a)|((u32)f2bf(b)<<16); }

#define NROWS 32768

// ---- expansion: x -> packed silu hi/lo (u32) + 8 basis bf16 (uint4) ----
// basis: pack [d0,d1,d2,d3] bf16 into u64, place at bit (i0-3)*16 of 128-bit window.
__device__ __forceinline__ void expand_vals(float x, u32& spk, uint4& bpk)
{
  float s = x * (1.0f/(1.0f+__expf(-x)));
  u16 uh = f2bf(s);
  u16 ul = f2bf(s - bf2f(uh));
  spk = (u32)uh | ((u32)ul<<16);
  float tp = __fmaf_rn(x, 2.5f, 5.5f);
  float fi = floorf(tp);
  float uu = tp - fi;
  float u2=uu*uu, u3=u2*uu, w1=1.0f-uu;
  const float c6 = 0.16666666666666666f;
  float d0 = w1*w1*w1*c6;
  float d1 = (4.0f-6.0f*u2+3.0f*u3)*c6;
  float d2 = (1.0f+3.0f*uu+3.0f*u2-3.0f*u3)*c6;
  float d3 = u3*c6;
  u64 dpk = (u64)pkbf(d0,d1) | ((u64)pkbf(d2,d3)<<32);
  int i0 = (int)fminf(fmaxf(fi,-20.f),20.f);
  int ss = (i0-3)*16;                    // valid x => ss in [-48,112]; else far out => zeros
  u64 A  = dpk << (ss & 63);
  u64 Bv = dpk >> ((64-ss) & 63);
  u64 Cv = dpk << ((ss-64) & 63);
  u64 Dv = dpk >> ((-ss) & 63);
  u64 lo = (ss>=0 && ss<64) ? A : ((ss<0 && ss>-64) ? Dv : 0ull);
  u64 hi = (ss>=64 && ss<128) ? Cv : ((ss>0 && ss<64) ? Bv : 0ull);
  bpk.x=(u32)lo; bpk.y=(u32)(lo>>32); bpk.z=(u32)hi; bpk.w=(u32)(hi>>32);
}

// ---------------- destination-major weight prep ----------------
// KE order per 16-feat chunk: [32 silu slots | 128 basis slots]  (KSC=5 ksteps)
// dest: ((kstep*NTILES + ntile)*64 + lane)*8 + j ; lane=(kpos>>3)*16+(o&15), kpos=k%32
struct PrepArgs {
  const float* bw[7]; const float* sw[7]; const float* sc[7];
  u16* w[7];
  int cin[7]; int coutr[7]; int ntsh[7];
  u32 elems[7];
};

__global__ __launch_bounds__(256) void prep_kernel(PrepArgs pa)
{
  u32 idx = blockIdx.x*256 + threadIdx.x;
  int L = 0;
  u32 off = idx;
  while (L < 6 && off >= pa.elems[L]) { off -= pa.elems[L]; ++L; }
  int j    = off & 7;
  int lane = (off>>3) & 63;
  u32 tl   = off >> 9;
  int ntsh = pa.ntsh[L];
  u32 kstep = tl >> ntsh;
  int ntile = (int)(tl & ((1u<<ntsh)-1u));
  int o    = ntile*16 + (lane&15);
  int kpos = (lane>>4)*8 + j;
  u32 c = kstep / 5u;
  int r = (int)(kstep - c*5u);
  int i, g; bool sil;
  if (r == 0){ i = (int)c*16 + (kpos>>1);          g = 0;        sil = true;  }
  else       { int kl=(r-1)*32+kpos; i=(int)c*16+(kl>>3); g=kl&7; sil = false; }
  float v = 0.f;
  if (o < pa.coutr[L]) {
    size_t e = (size_t)o*pa.cin[L] + i;
    v = sil ? pa.bw[L][e] : pa.sw[L][e*8+g]*pa.sc[L][e];
  }
  pa.w[L][off] = f2bf(v);
}

// ---------------- fused expand + MFMA layer: double-buffered 16-feat chunks ----------------
// 512 thr = 8 waves; each wave: all 4 m-tiles x NT col-tiles (rg-free for COUT>=128).
// IN_MODE: 0=f32, 1=bf16   OUT_MODE: 0=f32, 1=bf16
template<int CIN,int COUT,int IN_MODE,int OUT_MODE>
__global__ __launch_bounds__(512,4) void kan_layer(const void* __restrict__ hin_,
    const u16* __restrict__ W, void* __restrict__ hout_)
{
  constexpr int NCH = CIN/16;
  constexpr int TOTK = NCH*5;
  constexpr int NTILES = COUT/16;
  constexpr int NT = (COUT>=128)? COUT/128 : 1;
  constexpr int SROW=20, BROW=68, BOFF=64*SROW;
  constexpr int CHUNK = BOFF + 64*BROW;          // 5632 dw = 22528 B
  __shared__ u32 buf[2][CHUNK];                  // 45056 B

  const int b0 = blockIdx.x*64;
  const int tid = threadIdx.x;
  const int wave = tid>>6, lane = tid&63, m = lane&15, quad = lane>>4;

  const u16*   __restrict__ hb = (const u16*)hin_;
  const float* __restrict__ hf = (const float*)hin_;

  f32x4 acc[4][NT];
#pragma unroll
  for (int a=0;a<4;++a)
#pragma unroll
    for (int n=0;n<NT;++n) acc[a][n]=(f32x4){0.f,0.f,0.f,0.f};

  bf16x8 bbuf[3][NT];
  auto loadB = [&](int kstep, bf16x8* dst){
    if (kstep < TOTK){
#pragma unroll
      for (int nt=0; nt<NT; ++nt)
        dst[nt] = *(const bf16x8*)(W + (((size_t)kstep*NTILES + ((wave*NT+nt)&(NTILES-1)))*64 + lane)*8);
    }
  };
  loadB(0, bbuf[0]); loadB(1, bbuf[1]);

  float xb[2][2];
  auto loadX = [&](int kc, float* dst){
#pragma unroll
    for (int t=0;t<2;++t){
      int task = t*512+tid, row = task>>4, f = task&15;
      int gi = (b0+row)*CIN + kc*16 + f;
      dst[t] = (IN_MODE==0)? hf[gi] : bf2f(hb[gi]);
    }
  };
  auto expandChunk = [&](const float* xc, u32* dstb){
#pragma unroll
    for (int t=0;t<2;++t){
      int task=t*512+tid, row=task>>4, f=task&15;
      u32 spk; uint4 bpk;
      expand_vals(xc[t], spk, bpk);
      dstb[row*SROW + f] = spk;
      *(uint4*)&dstb[BOFF + row*BROW + f*4] = bpk;
    }
  };

  loadX(0, xb[0]);
  expandChunk(xb[0], buf[0]);
  loadX(1, xb[1]);
  __syncthreads();

  for (int kc=0; kc<NCH; ++kc){
    u32* cur = buf[kc&1];
    u32* nxt = buf[(kc+1)&1];
    if (kc+1 < NCH) expandChunk(xb[(kc+1)&1], nxt);
    if (kc+2 < NCH) loadX(kc+2, xb[kc&1]);
#pragma unroll
    for (int ks=0; ks<5; ++ks){
      const int kstep = kc*5 + ks;
      loadB(kstep+2, bbuf[2]);
      bf16x8 af[4];
#pragma unroll
      for (int mt=0; mt<4; ++mt){
        int row = mt*16 + m;
        af[mt] = (ks==0)
          ? *(const bf16x8*)&cur[row*SROW + quad*4]
          : *(const bf16x8*)&cur[BOFF + row*BROW + (ks-1)*16 + quad*4];
      }
#pragma unroll
      for (int nt=0; nt<NT; ++nt)
#pragma unroll
        for (int mt=0; mt<4; ++mt)
          acc[mt][nt] = __builtin_amdgcn_mfma_f32_16x16x32_bf16(af[mt], bbuf[0][nt], acc[mt][nt],0,0,0);
#pragma unroll
      for (int nt=0; nt<NT; ++nt){ bbuf[0][nt]=bbuf[1][nt]; bbuf[1][nt]=bbuf[2][nt]; }
    }
    __syncthreads();
  }

  // epilogue: C/D col=lane&15, row=quad*4+r; gate duplicate waves (COUT=64)
  if (wave*NT < NTILES){
#pragma unroll
    for (int mt=0; mt<4; ++mt)
#pragma unroll
      for (int nt=0; nt<NT; ++nt)
#pragma unroll
        for (int r=0; r<4; ++r){
          size_t off = (size_t)(b0 + mt*16 + quad*4 + r)*COUT + ((wave*NT+nt)&(NTILES-1))*16 + m;
          if constexpr (OUT_MODE==0) ((float*)hout_)[off] = acc[mt][nt][r];
          else                       ((u16*)hout_)[off]   = f2bf(acc[mt][nt][r]);
        }
  }
}

// ---------------- fused tail: h2 -> {L3->L4->adv , L5->L6->val} ----------------
template<int IN_MODE>
__global__ __launch_bounds__(512,4) void tail_kernel(const void* __restrict__ h2_,
  const u16* __restrict__ W3, const u16* __restrict__ W4,
  const u16* __restrict__ W5, const u16* __restrict__ W6,
  float* __restrict__ out_adv, float* __restrict__ out_val)
{
  constexpr int SROW=20, BROW=68, BOFF=64*20;
  __shared__ u32   Aexp[BOFF + 64*BROW];         // 22528 B
  __shared__ float hA[64*65], hV[64*65];         // 2 x 16640 B

  const int b0 = blockIdx.x*64;
  const int tid = threadIdx.x;
  const int wave = tid>>6, lane = tid&63, m = lane&15, quad = lane>>4;
  const int rg = wave>>2, cg = wave&3;

  const u16*   __restrict__ hb = (const u16*)h2_;
  const float* __restrict__ hf = (const float*)h2_;

  // ---- phase A: expand h2 once, accumulate L3 & L5 ----
  f32x4 a3[2], a5[2];
#pragma unroll
  for (int mt=0;mt<2;++mt){ a3[mt]=(f32x4){0,0,0,0}; a5[mt]=(f32x4){0,0,0,0}; }

  bf16x8 w3b[3], w5b[3];
  auto loadB2 = [&](int kstep, int d){
    if (kstep < 20){
      size_t bi = (((size_t)kstep*4 + cg)*64 + lane)*8;
      w3b[d] = *(const bf16x8*)(W3+bi);
      w5b[d] = *(const bf16x8*)(W5+bi);
    }
  };
  loadB2(0,0); loadB2(1,1);

  float xb[2][2];
  auto loadX = [&](int kc, float* dst){
#pragma unroll
    for (int t=0;t<2;++t){
      int task = t*512+tid, row=task>>4, f=task&15;
      int gi = (b0+row)*64 + kc*16 + f;
      dst[t] = (IN_MODE==0)? hf[gi] : bf2f(hb[gi]);
    }
  };
  loadX(0, xb[0]);

  for (int kc=0; kc<4; ++kc){
    const float* xc = xb[kc&1];
#pragma unroll
    for (int t=0;t<2;++t){
      int task=t*512+tid, row=task>>4, f=task&15;
      u32 spk; uint4 bpk;
      expand_vals(xc[t], spk, bpk);
      Aexp[row*SROW + f] = spk;
      *(uint4*)&Aexp[BOFF + row*BROW + f*4] = bpk;
    }
    if (kc+1 < 4) loadX(kc+1, xb[(kc+1)&1]);
    __syncthreads();
#pragma unroll
    for (int ks=0; ks<5; ++ks){
      const int kstep = kc*5 + ks;
      loadB2(kstep+2, 2);
      bf16x8 af[2];
#pragma unroll
      for (int mt=0; mt<2; ++mt){
        int row = rg*32 + mt*16 + m;
        af[mt] = (ks==0)
          ? *(const bf16x8*)&Aexp[row*SROW + quad*4]
          : *(const bf16x8*)&Aexp[BOFF + row*BROW + (ks-1)*16 + quad*4];
      }
#pragma unroll
      for (int mt=0; mt<2; ++mt){
        a3[mt] = __builtin_amdgcn_mfma_f32_16x16x32_bf16(af[mt], w3b[0], a3[mt],0,0,0);
        a5[mt] = __builtin_amdgcn_mfma_f32_16x16x32_bf16(af[mt], w5b[0], a5[mt],0,0,0);
      }
      w3b[0]=w3b[1]; w3b[1]=w3b[2]; w5b[0]=w5b[1]; w5b[1]=w5b[2];
    }
    __syncthreads();
  }
#pragma unroll
  for (int mt=0;mt<2;++mt)
#pragma unroll
    for (int r=0;r<4;++r){
      int row = rg*32 + mt*16 + quad*4 + r;
      hA[row*65 + cg*16 + m] = a3[mt][r];
      hV[row*65 + cg*16 + m] = a5[mt][r];
    }
  __syncthreads();

  // ---- phase B1: a3 -> L4 -> advantage ----
  f32x4 a4[2];
#pragma unroll
  for (int mt=0;mt<2;++mt) a4[mt]=(f32x4){0,0,0,0};
  bf16x8 w4b[3];
  auto loadB4 = [&](int kstep, int d){
    if (kstep < 20) w4b[d] = *(const bf16x8*)(W4 + (((size_t)kstep*4 + cg)*64 + lane)*8);
  };
  loadB4(0,0); loadB4(1,1);
  for (int kc=0; kc<4; ++kc){
#pragma unroll
    for (int t=0;t<2;++t){
      int task=t*512+tid, row=task>>4, f=task&15;
      u32 spk; uint4 bpk;
      expand_vals(hA[row*65 + kc*16 + f], spk, bpk);
      Aexp[row*SROW + f] = spk;
      *(uint4*)&Aexp[BOFF + row*BROW + f*4] = bpk;
    }
    __syncthreads();
#pragma unroll
    for (int ks=0; ks<5; ++ks){
      loadB4(kc*5+ks+2, 2);
      bf16x8 af[2];
#pragma unroll
      for (int mt=0; mt<2; ++mt){
        int row = rg*32 + mt*16 + m;
        af[mt] = (ks==0)
          ? *(const bf16x8*)&Aexp[row*SROW + quad*4]
          : *(const bf16x8*)&Aexp[BOFF + row*BROW + (ks-1)*16 + quad*4];
      }
#pragma unroll
      for (int mt=0; mt<2; ++mt)
        a4[mt] = __builtin_amdgcn_mfma_f32_16x16x32_bf16(af[mt], w4b[0], a4[mt],0,0,0);
      w4b[0]=w4b[1]; w4b[1]=w4b[2];
    }
    __syncthreads();
  }
  {
    int col = cg*16 + m;
    if (col < 18){
#pragma unroll
      for (int mt=0;mt<2;++mt)
#pragma unroll
        for (int r=0;r<4;++r)
          out_adv[(size_t)(b0 + rg*32 + mt*16 + quad*4 + r)*18 + col] = a4[mt][r];
    }
  }

  // ---- phase B2: v5 -> L6 -> value ----
  f32x4 a6[2];
#pragma unroll
  for (int mt=0;mt<2;++mt) a6[mt]=(f32x4){0,0,0,0};
  bf16x8 w6b[3];
  auto loadB6 = [&](int kstep, int d){
    if (kstep < 20) w6b[d] = *(const bf16x8*)(W6 + (((size_t)kstep*4 + cg)*64 + lane)*8);
  };
  loadB6(0,0); loadB6(1,1);
  for (int kc=0; kc<4; ++kc){
#pragma unroll
    for (int t=0;t<2;++t){
      int task=t*512+tid, row=task>>4, f=task&15;
      u32 spk; uint4 bpk;
      expand_vals(hV[row*65 + kc*16 + f], spk, bpk);
      Aexp[row*SROW + f] = spk;
      *(uint4*)&Aexp[BOFF + row*BROW + f*4] = bpk;
    }
    __syncthreads();
#pragma unroll
    for (int ks=0; ks<5; ++ks){
      loadB6(kc*5+ks+2, 2);
      bf16x8 af[2];
#pragma unroll
      for (int mt=0; mt<2; ++mt){
        int row = rg*32 + mt*16 + m;
        af[mt] = (ks==0)
          ? *(const bf16x8*)&Aexp[row*SROW + quad*4]
          : *(const bf16x8*)&Aexp[BOFF + row*BROW + (ks-1)*16 + quad*4];
      }
#pragma unroll
      for (int mt=0; mt<2; ++mt)
        a6[mt] = __builtin_amdgcn_mfma_f32_16x16x32_bf16(af[mt], w6b[0], a6[mt],0,0,0);
      w6b[0]=w6b[1]; w6b[1]=w6b[2];
    }
    __syncthreads();
  }
  if (cg==0 && m==0){
#pragma unroll
    for (int mt=0;mt<2;++mt)
#pragma unroll
      for (int r=0;r<4;++r)
        out_val[b0 + rg*32 + mt*16 + quad*4 + r] = a6[mt][r];
  }
}

extern "C" void kernel_launch(void* const* d_in, const int* in_sizes, int n_in,
                              void* d_out, int out_size, void* d_ws, size_t ws_size,
                              hipStream_t stream)
{
  (void)in_sizes; (void)n_in; (void)out_size;
  char* ws = (char*)d_ws;

  const size_t wbytes[7] = {655360u, 1310720u, 327680u, 81920u, 81920u, 81920u, 81920u};
  const bool midf32 = ws_size >= 78118912u;

  u16* W[7];
  char *h0, *h1, *h2;
  if (midf32) {
    h0 = ws;                       // 32768x256 f32
    h1 = h0 + 33554432u;
    h2 = h1 + 33554432u;           // 32768x64 f32
    size_t off = 75497472u;
    for (int l=0;l<7;++l){ W[l] = (u16*)(ws+off); off += wbytes[l]; }
  } else {
    h0 = ws;                       // bf16 fallback
    h1 = h0 + 16777216u;
    h2 = h1 + 16777216u;
    size_t off = 37748736u;
    for (int l=0;l<7;++l){ W[l] = (u16*)(ws+off); off += wbytes[l]; }
  }

  PrepArgs pa;
  const int cins[7]   = {128,256,256,64,64,64,64};
  const int coutr[7]  = {256,256,64,64,18,64,1};
  const int ntsh[7]   = {4,4,2,2,2,2,2};
  const u32 elems[7]  = {327680u,655360u,163840u,40960u,40960u,40960u,40960u};
  for (int l=0;l<7;++l){
    pa.bw[l] = (const float*)d_in[1+3*l];
    pa.sw[l] = (const float*)d_in[2+3*l];
    pa.sc[l] = (const float*)d_in[3+3*l];
    pa.w[l]  = W[l];
    pa.cin[l]=cins[l]; pa.coutr[l]=coutr[l]; pa.ntsh[l]=ntsh[l];
    pa.elems[l]=elems[l];
  }
  prep_kernel<<<5120, 256, 0, stream>>>(pa);

  dim3 g(NROWS/64), b(512);
  float* out_adv = (float*)d_out;
  float* out_val = (float*)d_out + (size_t)NROWS*18;
  if (midf32) {
    kan_layer<128,256,0,0><<<g,b,0,stream>>>(d_in[0], W[0], h0);
    kan_layer<256,256,0,0><<<g,b,0,stream>>>(h0, W[1], h1);
    kan_layer<256, 64,0,0><<<g,b,0,stream>>>(h1, W[2], h2);
    tail_kernel<0><<<g,b,0,stream>>>(h2, W[3], W[4], W[5], W[6], out_adv, out_val);
  } else {
    kan_layer<128,256,0,1><<<g,b,0,stream>>>(d_in[0], W[0], h0);
    kan_layer<256,256,1,1><<<g,b,0,stream>>>(h0, W[1], h1);
    kan_layer<256, 64,1,1><<<g,b,0,stream>>>(h1, W[2], h2);
    tail_kernel<1><<<g,b,0,stream>>>(h2, W[3], W[4], W[5], W[6], out_adv, out_val);
  }
}

// Round 7
// 231.139 us; speedup vs baseline: 2.3329x; 1.0328x over previous
//
#include <hip/hip_runtime.h>

typedef unsigned short u16;
typedef unsigned int   u32;
typedef unsigned long long u64;
typedef __bf16 bf16;
typedef float f32x4  __attribute__((ext_vector_type(4)));
typedef bf16  bf16x8 __attribute__((ext_vector_type(8)));

__device__ __forceinline__ float bf2f(u16 u){ return (float)__builtin_bit_cast(bf16,u); }
__device__ __forceinline__ u16   f2bf(float f){ return __builtin_bit_cast(u16,(bf16)f); }
__device__ __forceinline__ u32   pkbf(float a,float b){ return (u32)f2bf(a)|((u32)f2bf(b)<<16); }

#define NROWS 32768

// ---- basis: 8 bf16 slots, NO c6 (folded into B); d2(u)=d1(1-u), d0=w1^3, d3=u^3 ----
__device__ __forceinline__ uint4 basis_pk(float x)
{
  float tp  = __fmaf_rn(x, 2.5f, 5.5f);
  float tpc = fminf(fmaxf(tp, -1.0f), 12.0f);   // out-of-range -> window miss -> zeros
  float fi  = floorf(tpc);
  float uu  = tpc - fi;
  int   i0  = (int)fi;
  float u2 = uu*uu, u3 = u2*uu, w1 = 1.0f-uu, w2 = w1*w1, w3 = w2*w1;
  float d1 = __fmaf_rn(3.0f, u3, __fmaf_rn(-6.0f, u2, 4.0f));
  float d2 = __fmaf_rn(3.0f, w3, __fmaf_rn(-6.0f, w2, 4.0f));
  u64 dpk = (u64)pkbf(w3, d1) | ((u64)pkbf(d2, u3) << 32);
  int ss = i0*16 - 48;
  u64 A  = dpk << (ss & 63);
  u64 Bv = dpk >> ((64-ss) & 63);
  u64 Cv = dpk << ((ss-64) & 63);
  u64 Dv = dpk >> ((-ss) & 63);
  u64 lo = (ss>=0 && ss<64)   ? A  : ((ss<0 && ss>-64) ? Dv : 0ull);
  u64 hi = (ss>=64 && ss<128) ? Cv : ((ss>0 && ss<64)  ? Bv : 0ull);
  uint4 r; r.x=(u32)lo; r.y=(u32)(lo>>32); r.z=(u32)hi; r.w=(u32)(hi>>32);
  return r;
}

// main-layer expansion: single silu slot + bases
__device__ __forceinline__ void expand9(float x, u16& sil, uint4& bpk)
{
  float s = x * (1.0f/(1.0f+__expf(-x)));
  sil = f2bf(s);
  bpk = basis_pk(x);
}
// tail expansion: silu hi/lo pair + bases
__device__ __forceinline__ void expand10(float x, u32& spk, uint4& bpk)
{
  float s = x * (1.0f/(1.0f+__expf(-x)));
  u16 uh = f2bf(s);
  u16 ul = f2bf(s - bf2f(uh));
  spk = (u32)uh | ((u32)ul<<16);
  bpk = basis_pk(x);
}

// ---------------- destination-major weight prep, two formats ----------------
// fmt0 (main): 32-feat chunk = [32 silu | 256 basis] = 9 ksteps
// fmt1 (tail): 16-feat chunk = [32 silu(hi/lo dup) | 128 basis] = 5 ksteps
// dest: ((kstep*NTILES + ntile)*64 + lane)*8 + j ; lane=(kpos>>3)*16+(o&15)
struct PrepArgs {
  const float* bw[7]; const float* sw[7]; const float* sc[7];
  u16* w[7];
  int cin[7]; int coutr[7]; int ntsh[7]; int fmt[7];
  u32 elems[7];
};

__global__ __launch_bounds__(256) void prep_kernel(PrepArgs pa)
{
  u32 idx = blockIdx.x*256 + threadIdx.x;
  int L = 0;
  u32 off = idx;
  while (L < 6 && off >= pa.elems[L]) { off -= pa.elems[L]; ++L; }
  int j    = off & 7;
  int lane = (off>>3) & 63;
  u32 tl   = off >> 9;
  int ntsh = pa.ntsh[L];
  u32 kstep = tl >> ntsh;
  int ntile = (int)(tl & ((1u<<ntsh)-1u));
  int o    = ntile*16 + (lane&15);
  int kpos = (lane>>4)*8 + j;
  int i = 0, g = 0; bool sil;
  if (pa.fmt[L] == 0){
    u32 c = kstep/9u; int r = (int)(kstep - c*9u);
    if (r == 0){ i = (int)c*32 + kpos; sil = true; }
    else { int kl=(r-1)*32+kpos; i=(int)c*32+(kl>>3); g=kl&7; sil = false; }
  } else {
    u32 c = kstep/5u; int r = (int)(kstep - c*5u);
    if (r == 0){ i = (int)c*16 + (kpos>>1); sil = true; }
    else { int kl=(r-1)*32+kpos; i=(int)c*16+(kl>>3); g=kl&7; sil = false; }
  }
  float v = 0.f;
  if (o < pa.coutr[L]) {
    size_t e = (size_t)o*pa.cin[L] + i;
    v = sil ? pa.bw[L][e] : pa.sw[L][e*8+g]*pa.sc[L][e]*0.16666666666666666f;
  }
  pa.w[L][off] = f2bf(v);
}

// ---------------- fused expand + MFMA layer: double-buffered 32-feat chunks ----------------
// 512 thr = 8 waves; each wave: all 4 m-tiles x NT col-tiles.
template<int CIN,int COUT,int IN_MODE,int OUT_MODE>
__global__ __launch_bounds__(512,4) void kan_layer(const void* __restrict__ hin_,
    const u16* __restrict__ W, void* __restrict__ hout_)
{
  constexpr int NCH = CIN/32;
  constexpr int TOTK = NCH*9;
  constexpr int NTILES = COUT/16;
  constexpr int NT = (COUT>=128)? COUT/128 : 1;
  constexpr int SROW=20, BROW=132, BOFF=64*SROW;
  constexpr int CHUNK = BOFF + 64*BROW;          // 9728 dw = 38912 B
  __shared__ u32 buf[2][CHUNK];                  // 77824 B -> 2 blocks/CU

  const int b0 = blockIdx.x*64;
  const int tid = threadIdx.x;
  const int wave = tid>>6, lane = tid&63, m = lane&15, quad = lane>>4;

  const u16*   __restrict__ hb = (const u16*)hin_;
  const float* __restrict__ hf = (const float*)hin_;

  f32x4 acc[4][NT];
#pragma unroll
  for (int a=0;a<4;++a)
#pragma unroll
    for (int n=0;n<NT;++n) acc[a][n]=(f32x4){0.f,0.f,0.f,0.f};

  bf16x8 bbuf[3][NT];
  auto loadB = [&](int kstep, bf16x8* dst){
    if (kstep < TOTK){
#pragma unroll
      for (int nt=0; nt<NT; ++nt)
        dst[nt] = *(const bf16x8*)(W + (((size_t)kstep*NTILES + ((wave*NT+nt)&(NTILES-1)))*64 + lane)*8);
    }
  };
  loadB(0, bbuf[0]); loadB(1, bbuf[1]);

  float xb[2][4];
  auto loadX = [&](int kc, float* dst){
#pragma unroll
    for (int t=0;t<4;++t){
      int task = t*512+tid, row = task>>5, f = task&31;
      int gi = (b0+row)*CIN + kc*32 + f;
      dst[t] = (IN_MODE==0)? hf[gi] : bf2f(hb[gi]);
    }
  };
  auto expandChunk = [&](const float* xc, u32* dstb){
#pragma unroll
    for (int t=0;t<4;++t){
      int task=t*512+tid, row=task>>5, f=task&31;
      u16 sil; uint4 bpk;
      expand9(xc[t], sil, bpk);
      ((u16*)dstb)[row*(SROW*2) + f] = sil;
      *(uint4*)&dstb[BOFF + row*BROW + f*4] = bpk;
    }
  };

  loadX(0, xb[0]);
  expandChunk(xb[0], buf[0]);
  if (NCH > 1) loadX(1, xb[1]);
  __syncthreads();

  for (int kc=0; kc<NCH; ++kc){
    u32* cur = buf[kc&1];
    u32* nxt = buf[(kc+1)&1];
    if (kc+1 < NCH) expandChunk(xb[(kc+1)&1], nxt);
    if (kc+2 < NCH) loadX(kc+2, xb[kc&1]);
#pragma unroll
    for (int ks=0; ks<9; ++ks){
      const int kstep = kc*9 + ks;
      loadB(kstep+2, bbuf[2]);
      bf16x8 af[4];
#pragma unroll
      for (int mt=0; mt<4; ++mt){
        int row = mt*16 + m;
        af[mt] = (ks==0)
          ? *(const bf16x8*)&cur[row*SROW + quad*4]
          : *(const bf16x8*)&cur[BOFF + row*BROW + (ks-1)*16 + quad*4];
      }
#pragma unroll
      for (int nt=0; nt<NT; ++nt)
#pragma unroll
        for (int mt=0; mt<4; ++mt)
          acc[mt][nt] = __builtin_amdgcn_mfma_f32_16x16x32_bf16(af[mt], bbuf[0][nt], acc[mt][nt],0,0,0);
#pragma unroll
      for (int nt=0; nt<NT; ++nt){ bbuf[0][nt]=bbuf[1][nt]; bbuf[1][nt]=bbuf[2][nt]; }
    }
    __syncthreads();
  }

  // epilogue: C/D col=lane&15, row=quad*4+r; gate duplicate waves (COUT=64)
  if (wave*NT < NTILES){
#pragma unroll
    for (int mt=0; mt<4; ++mt)
#pragma unroll
      for (int nt=0; nt<NT; ++nt)
#pragma unroll
        for (int r=0; r<4; ++r){
          size_t off = (size_t)(b0 + mt*16 + quad*4 + r)*COUT + ((wave*NT+nt)&(NTILES-1))*16 + m;
          if constexpr (OUT_MODE==0) ((float*)hout_)[off] = acc[mt][nt][r];
          else                       ((u16*)hout_)[off]   = f2bf(acc[mt][nt][r]);
        }
  }
}

// ---------------- fused tail: h2 -> {L3->L4->adv , L5->L6->val} (fmt1 weights) ----------------
template<int IN_MODE>
__global__ __launch_bounds__(512,4) void tail_kernel(const void* __restrict__ h2_,
  const u16* __restrict__ W3, const u16* __restrict__ W4,
  const u16* __restrict__ W5, const u16* __restrict__ W6,
  float* __restrict__ out_adv, float* __restrict__ out_val)
{
  constexpr int SROW=20, BROW=68, BOFF=64*20;
  __shared__ u32   Aexp[BOFF + 64*BROW];         // 22528 B
  __shared__ float hA[64*65], hV[64*65];         // 2 x 16640 B

  const int b0 = blockIdx.x*64;
  const int tid = threadIdx.x;
  const int wave = tid>>6, lane = tid&63, m = lane&15, quad = lane>>4;
  const int rg = wave>>2, cg = wave&3;

  const u16*   __restrict__ hb = (const u16*)h2_;
  const float* __restrict__ hf = (const float*)h2_;

  // ---- phase A: expand h2 once, accumulate L3 & L5 ----
  f32x4 a3[2], a5[2];
#pragma unroll
  for (int mt=0;mt<2;++mt){ a3[mt]=(f32x4){0,0,0,0}; a5[mt]=(f32x4){0,0,0,0}; }

  bf16x8 w3b[3], w5b[3];
  auto loadB2 = [&](int kstep, int d){
    if (kstep < 20){
      size_t bi = (((size_t)kstep*4 + cg)*64 + lane)*8;
      w3b[d] = *(const bf16x8*)(W3+bi);
      w5b[d] = *(const bf16x8*)(W5+bi);
    }
  };
  loadB2(0,0); loadB2(1,1);

  float xb[2][2];
  auto loadX = [&](int kc, float* dst){
#pragma unroll
    for (int t=0;t<2;++t){
      int task = t*512+tid, row=task>>4, f=task&15;
      int gi = (b0+row)*64 + kc*16 + f;
      dst[t] = (IN_MODE==0)? hf[gi] : bf2f(hb[gi]);
    }
  };
  loadX(0, xb[0]);

  for (int kc=0; kc<4; ++kc){
    const float* xc = xb[kc&1];
#pragma unroll
    for (int t=0;t<2;++t){
      int task=t*512+tid, row=task>>4, f=task&15;
      u32 spk; uint4 bpk;
      expand10(xc[t], spk, bpk);
      Aexp[row*SROW + f] = spk;
      *(uint4*)&Aexp[BOFF + row*BROW + f*4] = bpk;
    }
    if (kc+1 < 4) loadX(kc+1, xb[(kc+1)&1]);
    __syncthreads();
#pragma unroll
    for (int ks=0; ks<5; ++ks){
      const int kstep = kc*5 + ks;
      loadB2(kstep+2, 2);
      bf16x8 af[2];
#pragma unroll
      for (int mt=0; mt<2; ++mt){
        int row = rg*32 + mt*16 + m;
        af[mt] = (ks==0)
          ? *(const bf16x8*)&Aexp[row*SROW + quad*4]
          : *(const bf16x8*)&Aexp[BOFF + row*BROW + (ks-1)*16 + quad*4];
      }
#pragma unroll
      for (int mt=0; mt<2; ++mt){
        a3[mt] = __builtin_amdgcn_mfma_f32_16x16x32_bf16(af[mt], w3b[0], a3[mt],0,0,0);
        a5[mt] = __builtin_amdgcn_mfma_f32_16x16x32_bf16(af[mt], w5b[0], a5[mt],0,0,0);
      }
      w3b[0]=w3b[1]; w3b[1]=w3b[2]; w5b[0]=w5b[1]; w5b[1]=w5b[2];
    }
    __syncthreads();
  }
#pragma unroll
  for (int mt=0;mt<2;++mt)
#pragma unroll
    for (int r=0;r<4;++r){
      int row = rg*32 + mt*16 + quad*4 + r;
      hA[row*65 + cg*16 + m] = a3[mt][r];
      hV[row*65 + cg*16 + m] = a5[mt][r];
    }
  __syncthreads();

  // ---- phase B1: a3 -> L4 -> advantage ----
  f32x4 a4[2];
#pragma unroll
  for (int mt=0;mt<2;++mt) a4[mt]=(f32x4){0,0,0,0};
  bf16x8 w4b[3];
  auto loadB4 = [&](int kstep, int d){
    if (kstep < 20) w4b[d] = *(const bf16x8*)(W4 + (((size_t)kstep*4 + cg)*64 + lane)*8);
  };
  loadB4(0,0); loadB4(1,1);
  for (int kc=0; kc<4; ++kc){
#pragma unroll
    for (int t=0;t<2;++t){
      int task=t*512+tid, row=task>>4, f=task&15;
      u32 spk; uint4 bpk;
      expand10(hA[row*65 + kc*16 + f], spk, bpk);
      Aexp[row*SROW + f] = spk;
      *(uint4*)&Aexp[BOFF + row*BROW + f*4] = bpk;
    }
    __syncthreads();
#pragma unroll
    for (int ks=0; ks<5; ++ks){
      loadB4(kc*5+ks+2, 2);
      bf16x8 af[2];
#pragma unroll
      for (int mt=0; mt<2; ++mt){
        int row = rg*32 + mt*16 + m;
        af[mt] = (ks==0)
          ? *(const bf16x8*)&Aexp[row*SROW + quad*4]
          : *(const bf16x8*)&Aexp[BOFF + row*BROW + (ks-1)*16 + quad*4];
      }
#pragma unroll
      for (int mt=0; mt<2; ++mt)
        a4[mt] = __builtin_amdgcn_mfma_f32_16x16x32_bf16(af[mt], w4b[0], a4[mt],0,0,0);
      w4b[0]=w4b[1]; w4b[1]=w4b[2];
    }
    __syncthreads();
  }
  {
    int col = cg*16 + m;
    if (col < 18){
#pragma unroll
      for (int mt=0;mt<2;++mt)
#pragma unroll
        for (int r=0;r<4;++r)
          out_adv[(size_t)(b0 + rg*32 + mt*16 + quad*4 + r)*18 + col] = a4[mt][r];
    }
  }

  // ---- phase B2: v5 -> L6 -> value ----
  f32x4 a6[2];
#pragma unroll
  for (int mt=0;mt<2;++mt) a6[mt]=(f32x4){0,0,0,0};
  bf16x8 w6b[3];
  auto loadB6 = [&](int kstep, int d){
    if (kstep < 20) w6b[d] = *(const bf16x8*)(W6 + (((size_t)kstep*4 + cg)*64 + lane)*8);
  };
  loadB6(0,0); loadB6(1,1);
  for (int kc=0; kc<4; ++kc){
#pragma unroll
    for (int t=0;t<2;++t){
      int task=t*512+tid, row=task>>4, f=task&15;
      u32 spk; uint4 bpk;
      expand10(hV[row*65 + kc*16 + f], spk, bpk);
      Aexp[row*SROW + f] = spk;
      *(uint4*)&Aexp[BOFF + row*BROW + f*4] = bpk;
    }
    __syncthreads();
#pragma unroll
    for (int ks=0; ks<5; ++ks){
      loadB6(kc*5+ks+2, 2);
      bf16x8 af[2];
#pragma unroll
      for (int mt=0; mt<2; ++mt){
        int row = rg*32 + mt*16 + m;
        af[mt] = (ks==0)
          ? *(const bf16x8*)&Aexp[row*SROW + quad*4]
          : *(const bf16x8*)&Aexp[BOFF + row*BROW + (ks-1)*16 + quad*4];
      }
#pragma unroll
      for (int mt=0; mt<2; ++mt)
        a6[mt] = __builtin_amdgcn_mfma_f32_16x16x32_bf16(af[mt], w6b[0], a6[mt],0,0,0);
      w6b[0]=w6b[1]; w6b[1]=w6b[2];
    }
    __syncthreads();
  }
  if (cg==0 && m==0){
#pragma unroll
    for (int mt=0;mt<2;++mt)
#pragma unroll
      for (int r=0;r<4;++r)
        out_val[b0 + rg*32 + mt*16 + quad*4 + r] = a6[mt][r];
  }
}

extern "C" void kernel_launch(void* const* d_in, const int* in_sizes, int n_in,
                              void* d_out, int out_size, void* d_ws, size_t ws_size,
                              hipStream_t stream)
{
  (void)in_sizes; (void)n_in; (void)out_size;
  char* ws = (char*)d_ws;

  // W layouts: L0 36 ksteps x16 tiles, L1 72x16, L2 72x4, L3-6 20x4
  const size_t wbytes[7] = {589824u, 1179648u, 294912u, 81920u, 81920u, 81920u, 81920u};
  const bool midf32 = ws_size >= 77889536u;

  u16* W[7];
  char *h0, *h1, *h2;
  if (midf32) {
    h0 = ws;                       // 32768x256 f32
    h1 = h0 + 33554432u;
    h2 = h1 + 33554432u;           // 32768x64 f32
    size_t off = 75497472u;
    for (int l=0;l<7;++l){ W[l] = (u16*)(ws+off); off += wbytes[l]; }
  } else {
    h0 = ws;                       // bf16 fallback
    h1 = h0 + 16777216u;
    h2 = h1 + 16777216u;
    size_t off = 37748736u;
    for (int l=0;l<7;++l){ W[l] = (u16*)(ws+off); off += wbytes[l]; }
  }

  PrepArgs pa;
  const int cins[7]   = {128,256,256,64,64,64,64};
  const int coutr[7]  = {256,256,64,64,18,64,1};
  const int ntsh[7]   = {4,4,2,2,2,2,2};
  const int fmts[7]   = {0,0,0,1,1,1,1};
  const u32 elems[7]  = {294912u,589824u,147456u,40960u,40960u,40960u,40960u};
  for (int l=0;l<7;++l){
    pa.bw[l] = (const float*)d_in[1+3*l];
    pa.sw[l] = (const float*)d_in[2+3*l];
    pa.sc[l] = (const float*)d_in[3+3*l];
    pa.w[l]  = W[l];
    pa.cin[l]=cins[l]; pa.coutr[l]=coutr[l]; pa.ntsh[l]=ntsh[l]; pa.fmt[l]=fmts[l];
    pa.elems[l]=elems[l];
  }
  prep_kernel<<<4672, 256, 0, stream>>>(pa);

  dim3 g(NROWS/64), b(512);
  float* out_adv = (float*)d_out;
  float* out_val = (float*)d_out + (size_t)NROWS*18;
  if (midf32) {
    kan_layer<128,256,0,0><<<g,b,0,stream>>>(d_in[0], W[0], h0);
    kan_layer<256,256,0,0><<<g,b,0,stream>>>(h0, W[1], h1);
    kan_layer<256, 64,0,0><<<g,b,0,stream>>>(h1, W[2], h2);
    tail_kernel<0><<<g,b,0,stream>>>(h2, W[3], W[4], W[5], W[6], out_adv, out_val);
  } else {
    kan_layer<128,256,0,1><<<g,b,0,stream>>>(d_in[0], W[0], h0);
    kan_layer<256,256,1,1><<<g,b,0,stream>>>(h0, W[1], h1);
    kan_layer<256, 64,1,1><<<g,b,0,stream>>>(h1, W[2], h2);
    tail_kernel<1><<<g,b,0,stream>>>(h2, W[3], W[4], W[5], W[6], out_adv, out_val);
  }
}